// Round 11
// baseline (786.012 us; speedup 1.0000x reference)
//
#include <hip/hip_runtime.h>
#include <math.h>

// RVQECell on MI355X.
// State: [B=32][2^19] fp32. Lane l <-> state bit (18-l). inout = bits 13..18,
// work = bits 1..12, ancilla = bit 0 (spectator).
//
// R16 (vs R15 failed; R10 @ 328 = best):
//  R15 post-mortem: absmax error 1.6479e-2 == max of uniform 64-bin probs
//  -> probs === 0 -> the cooperative kernel NEVER RAN (launch rejected,
//  most plausibly under graph capture; error code dropped). Fusion theory
//  untested. R16 = same fusion via a PERSISTENT software grid barrier:
//   - ordinary <<<512,256>>> launch (capture-safe by construction);
//   - 64 KiB LDS/block -> exactly 2 blocks/CU x 256 CU = 512 co-resident
//     (LDS-limited; launch_bounds(256,2) caps VGPR <= 256, no spill);
//   - barrier: agent-scope ACQ_REL atomics (LLVM gfx950 emits L2
//     writeback/invalidate -> cross-XCD visibility for tab and psi);
//   - two one-shot counters in ws, zeroed via hipMemsetAsync per launch
//     (capture-legal; harness itself enqueues memsets) -> no ABA.
//  Phases T/M/O byte-identical math to R10/R14.

#define BIAS_F 1.57079632679489662f

typedef float v4f __attribute__((ext_vector_type(4)));

__device__ __forceinline__ float4 ntload4(const float* p) {
    v4f v = __builtin_nontemporal_load((const v4f*)p);
    return make_float4(v.x, v.y, v.z, v.w);
}
__device__ __forceinline__ void ntstore4(float* p, float4 f) {
    v4f v = {f.x, f.y, f.z, f.w};
    __builtin_nontemporal_store(v, (v4f*)p);
}

// ---- LDS bank swizzle: fold bits 7..5 into 4..2 (keeps float4 contiguity) ----
__device__ __forceinline__ int SW(int i) { return i ^ ((i >> 3) & 0x1C); }
__device__ __forceinline__ float4 ldsld4(const float* st, int i) {
    return *(const float4*)&st[SW(i)];
}
__device__ __forceinline__ void ldsst4(float* st, int i, float4 v) {
    *(float4*)&st[SW(i)] = v;
}

#define LD2(p) (*(const float2*)(p))
#define LD4(p) (*(const float4*)(p))

// rotation on pairs (A.k, B.k); e = (c01,s01,c23,s23); .x/.y share angle (bit0)
__device__ __forceinline__ void rot4(float4& A, float4& B, float4 e) {
    float ax = A.x, ay = A.y, az = A.z, aw = A.w;
    A.x = e.x * ax - e.y * B.x;  B.x = e.y * ax + e.x * B.x;
    A.y = e.x * ay - e.y * B.y;  B.y = e.y * ay + e.x * B.y;
    A.z = e.z * az - e.w * B.z;  B.z = e.w * az + e.z * B.z;
    A.w = e.z * aw - e.w * B.w;  B.w = e.w * aw + e.z * B.w;
}
// rotation within a quad: pairs (x,z),(y,w)  (target = amp bit 1)
__device__ __forceinline__ void rotq(float4& P, float c, float s) {
    float px = P.x, py = P.y;
    P.x = c * px - s * P.z;  P.z = s * px + c * P.z;
    P.y = c * py - s * P.w;  P.w = s * py + c * P.w;
}

// Persistent grid barrier: all 512 blocks resident (LDS-limited 2/CU).
// Agent-scope acq_rel -> L2 writeback/invalidate = cross-XCD visibility.
__device__ __forceinline__ void grid_barrier(unsigned* bar, unsigned nb) {
    __syncthreads();
    if (threadIdx.x == 0) {
        __hip_atomic_fetch_add(bar, 1u, __ATOMIC_ACQ_REL, __HIP_MEMORY_SCOPE_AGENT);
        while (__hip_atomic_load(bar, __ATOMIC_ACQUIRE, __HIP_MEMORY_SCOPE_AGENT) < nb) {
            __builtin_amdgcn_s_sleep(16);
        }
    }
    __syncthreads();
}

// Table layout: float2 tab2[n * 131072 + x] = {cos a, sin a}, n = 0..53.

// High pass, targets {PA,PA-1,PA-2}; unpacked (c,s) table regs (12 float4)
// loaded once, reused for both batch slots. t* point at float2 data
// (float-indexed: angle x lives at [2x]).
template <int PA, bool NEUR>
__device__ __forceinline__ void pass_hi2(float* l0, float* l1, int t8,
    const float* tA, const float* tB, const float* tC,
    float cA, float sA, float cB, float sB, float cC, float sC)
{
    const int lowb = PA - 4;
    const int low = t8 & ((1 << lowb) - 1);
    const int high = t8 >> lowb;
    const int i0 = (high << (PA + 1)) | (low << 2);
    const int x0 = (high << (PA - 1)) | (low << 1);
    const int oa = 1 << PA, ob = oa >> 1, oc = oa >> 2;
    const int dhi = oa >> 2, dlo = oa >> 3;
    float4 ea00, ea01, ea10, ea11, eb00, eb01, eb10, eb11, ec00, ec01, ec10, ec11;
    if (NEUR) {
        ea00 = LD4(&tA[2 * x0]);            ea01 = LD4(&tA[2 * (x0 + dlo)]);
        ea10 = LD4(&tA[2 * (x0 + dhi)]);    ea11 = LD4(&tA[2 * (x0 + dhi + dlo)]);
        eb00 = LD4(&tB[2 * x0]);            eb01 = LD4(&tB[2 * (x0 + dlo)]);
        eb10 = LD4(&tB[2 * (x0 + dhi)]);    eb11 = LD4(&tB[2 * (x0 + dhi + dlo)]);
        ec00 = LD4(&tC[2 * x0]);            ec01 = LD4(&tC[2 * (x0 + dlo)]);
        ec10 = LD4(&tC[2 * (x0 + dhi)]);    ec11 = LD4(&tC[2 * (x0 + dhi + dlo)]);
    } else {
        ea00 = ea01 = ea10 = ea11 = make_float4(cA, sA, cA, sA);
        eb00 = eb01 = eb10 = eb11 = make_float4(cB, sB, cB, sB);
        ec00 = ec01 = ec10 = ec11 = make_float4(cC, sC, cC, sC);
    }
#pragma unroll
    for (int s = 0; s < 2; ++s) {
        float* sl = (s == 0) ? l0 : l1;
        float4 Q000 = ldsld4(sl, i0),            Q001 = ldsld4(sl, i0 + oc);
        float4 Q010 = ldsld4(sl, i0 + ob),       Q011 = ldsld4(sl, i0 + ob + oc);
        float4 Q100 = ldsld4(sl, i0 + oa),       Q101 = ldsld4(sl, i0 + oa + oc);
        float4 Q110 = ldsld4(sl, i0 + oa + ob),  Q111 = ldsld4(sl, i0 + oa + ob + oc);
        // target PA
        rot4(Q000, Q100, ea00); rot4(Q001, Q101, ea01);
        rot4(Q010, Q110, ea10); rot4(Q011, Q111, ea11);
        // target PA-1
        rot4(Q000, Q010, eb00); rot4(Q001, Q011, eb01);
        rot4(Q100, Q110, eb10); rot4(Q101, Q111, eb11);
        // target PA-2
        rot4(Q000, Q001, ec00); rot4(Q010, Q011, ec01);
        rot4(Q100, Q101, ec10); rot4(Q110, Q111, ec11);
        ldsst4(sl, i0, Q000);            ldsst4(sl, i0 + oc, Q001);
        ldsst4(sl, i0 + ob, Q010);       ldsst4(sl, i0 + ob + oc, Q011);
        ldsst4(sl, i0 + oa, Q100);       ldsst4(sl, i0 + oa + oc, Q101);
        ldsst4(sl, i0 + oa + ob, Q110);  ldsst4(sl, i0 + oa + ob + oc, Q111);
    }
}

// Low pass, targets {3,2,1}. Thread owns amps i0..i0+31 (8 angles x0..x0+7).
template <bool NEUR>
__device__ __forceinline__ void pass_lo2(float* l0, float* l1, int t8,
    const float* tA, const float* tB, const float* tC,
    float cA, float sA, float cB, float sB, float cC, float sC)
{
    const int i0 = t8 << 5, x0 = t8 << 3;
    float4 ea0, ea1, ea2, ea3, eb0, eb1, eb2, eb3, ec0, ec1, ec2, ec3;
    if (NEUR) {
        ea0 = LD4(&tA[2 * x0]);      ea1 = LD4(&tA[2 * x0 + 4]);
        ea2 = LD4(&tA[2 * x0 + 8]);  ea3 = LD4(&tA[2 * x0 + 12]);
        eb0 = LD4(&tB[2 * x0]);      eb1 = LD4(&tB[2 * x0 + 4]);
        eb2 = LD4(&tB[2 * x0 + 8]);  eb3 = LD4(&tB[2 * x0 + 12]);
        ec0 = LD4(&tC[2 * x0]);      ec1 = LD4(&tC[2 * x0 + 4]);
        ec2 = LD4(&tC[2 * x0 + 8]);  ec3 = LD4(&tC[2 * x0 + 12]);
    } else {
        ea0 = ea1 = ea2 = ea3 = make_float4(cA, sA, cA, sA);
        eb0 = eb1 = eb2 = eb3 = make_float4(cB, sB, cB, sB);
        ec0 = ec1 = ec2 = ec3 = make_float4(cC, sC, cC, sC);
    }
#pragma unroll
    for (int s = 0; s < 2; ++s) {
        float* sl = (s == 0) ? l0 : l1;
        float4 Q0 = ldsld4(sl, i0),      Q1 = ldsld4(sl, i0 + 4);
        float4 Q2 = ldsld4(sl, i0 + 8),  Q3 = ldsld4(sl, i0 + 12);
        float4 Q4 = ldsld4(sl, i0 + 16), Q5 = ldsld4(sl, i0 + 20);
        float4 Q6 = ldsld4(sl, i0 + 24), Q7 = ldsld4(sl, i0 + 28);
        // target 3: pairs (k, k+2)
        rot4(Q0, Q2, ea0); rot4(Q1, Q3, ea1); rot4(Q4, Q6, ea2); rot4(Q5, Q7, ea3);
        // target 2: pairs (k, k+1)
        rot4(Q0, Q1, eb0); rot4(Q2, Q3, eb1); rot4(Q4, Q5, eb2); rot4(Q6, Q7, eb3);
        // target 1: in-quad
        rotq(Q0, ec0.x, ec0.y); rotq(Q1, ec0.z, ec0.w);
        rotq(Q2, ec1.x, ec1.y); rotq(Q3, ec1.z, ec1.w);
        rotq(Q4, ec2.x, ec2.y); rotq(Q5, ec2.z, ec2.w);
        rotq(Q6, ec3.x, ec3.y); rotq(Q7, ec3.z, ec3.w);
        ldsst4(sl, i0, Q0);      ldsst4(sl, i0 + 4, Q1);
        ldsst4(sl, i0 + 8, Q2);  ldsst4(sl, i0 + 12, Q3);
        ldsst4(sl, i0 + 16, Q4); ldsst4(sl, i0 + 20, Q5);
        ldsst4(sl, i0 + 24, Q6); ldsst4(sl, i0 + 28, Q7);
    }
}

// ============================ fused persistent kernel ============================
__global__ __launch_bounds__(256, 2) void mega_kernel(
    const float* __restrict__ batch,
    const float* __restrict__ w_in1, const float* __restrict__ w_in2,
    const float* __restrict__ w_u,
    const float* __restrict__ w_k1,  const float* __restrict__ w_k2,
    const float* __restrict__ w_out1, const float* __restrict__ w_out2,
    const int* __restrict__ inputs,
    float* __restrict__ tab, unsigned* __restrict__ bar,
    float* __restrict__ psi, float* __restrict__ probs)
{
    __shared__ __align__(16) float lds[16384];   // 64 KiB shared by all phases
    const int tid = threadIdx.x;
    const int blk = blockIdx.x;                  // 0..511

    // ================= Phase T: tables (hi = blk, n = 0..53) =================
    {
        const int hi = blk;                      // wave-uniform (9 bits)
        float bt[8];
#pragma unroll
        for (int j = 0; j < 8; ++j) bt[j] = (float)((tid >> (7 - j)) & 1);

#pragma unroll 1
        for (int n = 0; n < 54; ++n) {
            const float* th1;
            const float* th2;
            if (n < 12)      { th1 = w_in1 + n * 17;         th2 = w_in2 + n * 289; }
            else if (n < 48) { th1 = w_k1 + (n - 12) * 17;   th2 = w_k2 + (n - 12) * 289; }
            else             { th1 = w_out1 + (n - 48) * 17; th2 = w_out2 + (n - 48) * 289; }

            // uniform hi part: phi_hi + cross coefficients C[a]
            float phi_hi = BIAS_F;
            float C[8];
#pragma unroll
            for (int a = 0; a < 8; ++a) C[a] = th1[9 + a];
#pragma unroll
            for (int i = 0; i < 9; ++i) {
                if ((hi >> (8 - i)) & 1) {
                    float acc = th1[i];
#pragma unroll
                    for (int j = i + 1; j < 9; ++j)
                        if ((hi >> (8 - j)) & 1) acc += th2[i * 17 + j];
                    phi_hi += acc;
#pragma unroll
                    for (int a = 0; a < 8; ++a) C[a] += th2[i * 17 + 9 + a];
                }
            }
            // per-thread lo part: 36 FMA
            float phi = phi_hi;
#pragma unroll
            for (int a = 0; a < 8; ++a) {
                float acc = C[a];
#pragma unroll
                for (int b2 = a + 1; b2 < 8; ++b2)
                    acc += bt[b2] * th2[(9 + a) * 17 + 9 + b2];
                phi += bt[a] * acc;
            }
            float sp, cp;
            sincosf(phi, &sp, &cp);
            float c2 = cp * cp, s2 = sp * sp;
            float d = c2 * c2 + s2 * s2;           // >= 0.25 always
            float r = rsqrtf(d);
            r = r * (1.5f - 0.5f * d * r * r);     // one Newton step
            float2* dst = (float2*)tab +
                ((size_t)n * 131072 + (size_t)((hi << 8) | tid));
            *dst = make_float2(c2 * r, s2 * r);
        }
    }
    if (blk == 0) {   // zero probs for phase-O atomics
        float4 z = make_float4(0.f, 0.f, 0.f, 0.f);
        *(float4*)&probs[tid * 8] = z;
        *(float4*)&probs[tid * 8 + 4] = z;
    }
    grid_barrier(bar + 0, 512u);

    // ================= Phase M: main, units blk and blk+512 =================
    float* l0 = lds;
    float* l1 = lds + 8192;
#pragma unroll 1
    for (int u2 = 0; u2 < 2; ++u2) {
        const int unit = blk + u2 * 512;             // 0..1023
        const int xcd = unit & 7;
        const int vt = (xcd << 3) | ((unit >> 3) & 7);
        const int pair = unit >> 6;                  // 0..15
        const int t8 = tid;

        int bb[2], uu[2];
#pragma unroll
        for (int s = 0; s < 2; ++s) {
            int b = pair * 2 + s;
            int fb = 0;
#pragma unroll
            for (int i = 0; i < 6; ++i) fb |= (inputs[b * 6 + i] & 1) << (5 - i);
            bb[s] = b; uu[s] = vt ^ fb;
            const float* src = batch + ((size_t)b << 19) + ((size_t)uu[s] << 13);
            float* sl = (s == 0) ? l0 : l1;
#pragma unroll
            for (int k = 0; k < 8; ++k) {
                int i4 = (k * 256 + t8) * 4;
                float4 v = ntload4(&src[i4]);
                *(float4*)&sl[SW(i4)] = v;
            }
        }

        const float* tb = tab + ((size_t)vt << 12);
#define TN(j) (tb + (size_t)(j) * 262144)
#define BAR __syncthreads()
        BAR;
        // ---- input layer (neurons 0..11, target bit 12-j) ----
        pass_hi2<12, true>(l0, l1, t8, TN(0), TN(1), TN(2), 0,0,0,0,0,0);  BAR;
        pass_hi2<9,  true>(l0, l1, t8, TN(3), TN(4), TN(5), 0,0,0,0,0,0);  BAR;
        pass_hi2<6,  true>(l0, l1, t8, TN(6), TN(7), TN(8), 0,0,0,0,0,0);  BAR;
        pass_lo2<true>(l0, l1, t8, TN(9), TN(10), TN(11), 0,0,0,0,0,0);    BAR;

#pragma unroll 1
        for (int st2 = 0; st2 < 3; ++st2) {
            const float* wu = w_u + st2 * 12;
            float c0, s0, c1, s1, c2, s2;
            sincosf(wu[0], &s0, &c0); sincosf(wu[1], &s1, &c1); sincosf(wu[2], &s2, &c2);
            pass_hi2<12, false>(l0, l1, t8, 0,0,0, c0,s0, c1,s1, c2,s2);   BAR;
            sincosf(wu[3], &s0, &c0); sincosf(wu[4], &s1, &c1); sincosf(wu[5], &s2, &c2);
            pass_hi2<9, false>(l0, l1, t8, 0,0,0, c0,s0, c1,s1, c2,s2);    BAR;
            sincosf(wu[6], &s0, &c0); sincosf(wu[7], &s1, &c1); sincosf(wu[8], &s2, &c2);
            pass_hi2<6, false>(l0, l1, t8, 0,0,0, c0,s0, c1,s1, c2,s2);    BAR;
            sincosf(wu[9], &s0, &c0); sincosf(wu[10], &s1, &c1); sincosf(wu[11], &s2, &c2);
            pass_lo2<false>(l0, l1, t8, 0,0,0, c0,s0, c1,s1, c2,s2);       BAR;

            const int nb = 12 + st2 * 12;
            pass_hi2<12, true>(l0, l1, t8, TN(nb+0), TN(nb+1), TN(nb+2), 0,0,0,0,0,0); BAR;
            pass_hi2<9,  true>(l0, l1, t8, TN(nb+3), TN(nb+4), TN(nb+5), 0,0,0,0,0,0); BAR;
            pass_hi2<6,  true>(l0, l1, t8, TN(nb+6), TN(nb+7), TN(nb+8), 0,0,0,0,0,0); BAR;
            pass_lo2<true>(l0, l1, t8, TN(nb+9), TN(nb+10), TN(nb+11), 0,0,0,0,0,0);   BAR;
        }
#undef TN
#undef BAR

#pragma unroll
        for (int s = 0; s < 2; ++s) {
            float* dst = psi + ((size_t)bb[s] << 19) + ((size_t)uu[s] << 13);
            float* sl = (s == 0) ? l0 : l1;
#pragma unroll
            for (int k = 0; k < 8; ++k) {
                int i4 = (k * 256 + t8) * 4;
                float4 v = *(const float4*)&sl[SW(i4)];
                ntstore4(&dst[i4], v);
            }
        }
        __syncthreads();   // LDS reuse safe before next unit
    }
    grid_barrier(bar + 1, 512u);

    // ================= Phase O: out, units blk and blk+512 =================
    float* ts = lds;
#pragma unroll 1
    for (int u2 = 0; u2 < 2; ++u2) {
        __syncthreads();   // previous LDS use complete
        const int unit = blk + u2 * 512;             // 0..1023
        const int lane = tid & 63;
        const int wv = tid >> 6;
        const int b = unit >> 5;
        const int c0 = (unit & 31) << 8;
        float* gbase = psi + ((size_t)b << 19) + c0;

        // ---- load tile: wave wv rows wv*16..+15, lane l -> cols 4l..4l+3 ----
#pragma unroll
        for (int i = 0; i < 16; ++i) {
            int k = wv * 16 + i;
            float4 v = ntload4(&gbase[((size_t)k << 13) + lane * 4]);
            int f4 = lane ^ (k & 15);
            *(float4*)&ts[k * 256 + f4 * 4] = v;
        }
        __syncthreads();

        // ---- column phase: thread owns col c = tid ----
        float a[64];
#pragma unroll
        for (int k = 0; k < 64; ++k) a[k] = ts[k * 256 + (tid ^ ((k & 15) << 2))];
        const int w12 = (c0 | tid) >> 1;

#define OSTAGE(J) { \
    const float* tj = tab + 2u * ((size_t)(48 + (J)) * 131072 + (size_t)w12); \
    _Pragma("unroll") \
    for (int h = 0; h < 2; ++h) { \
        float2 ev[16]; \
        _Pragma("unroll") \
        for (int m = 0; m < 16; ++m) ev[m] = LD2(&tj[(size_t)(h * 16 + m) << 13]); \
        _Pragma("unroll") \
        for (int m = 0; m < 16; ++m) { \
            const int mm = h * 16 + m; \
            const int q = 5 - (J); \
            const int k0 = ((mm >> q) << (q + 1)) | (mm & ((1 << q) - 1)); \
            const int k1 = k0 | (1 << q); \
            float2 e = ev[m]; \
            float A0 = a[k0], A1 = a[k1]; \
            a[k0] = e.x * A0 - e.y * A1; \
            a[k1] = e.y * A0 + e.x * A1; } } }
        OSTAGE(0) OSTAGE(1) OSTAGE(2) OSTAGE(3) OSTAGE(4) OSTAGE(5)
#undef OSTAGE

#pragma unroll
        for (int k = 0; k < 64; ++k) ts[k * 256 + (tid ^ ((k & 15) << 2))] = a[k];
        __syncthreads();

        // ---- store rows back (float4) ----
#pragma unroll
        for (int i = 0; i < 16; ++i) {
            int k = wv * 16 + i;
            int f4 = lane ^ (k & 15);
            float4 v = *(const float4*)&ts[k * 256 + f4 * 4];
            ntstore4(&gbase[((size_t)k << 13) + lane * 4], v);
        }

        // ---- probs: thread (seg,k) sums 64 cols, rotated start ----
        const int k6 = tid & 63, seg = tid >> 6;
        float p = 0.f;
#pragma unroll
        for (int j = 0; j < 64; ++j) {
            int c = seg * 64 + ((j + k6) & 63);
            float v = ts[k6 * 256 + (c ^ ((k6 & 15) << 2))];
            p += v * v;
        }
        atomicAdd(&probs[b * 64 + k6], p);
    }
}

// ============================ launch ============================
extern "C" void kernel_launch(void* const* d_in, const int* in_sizes, int n_in,
                              void* d_out, int out_size, void* d_ws, size_t ws_size,
                              hipStream_t stream)
{
    const float* batch  = (const float*)d_in[0];
    const float* w_in1  = (const float*)d_in[1];
    const float* w_in2  = (const float*)d_in[2];
    const float* w_u    = (const float*)d_in[3];
    const float* w_k1   = (const float*)d_in[4];
    const float* w_k2   = (const float*)d_in[5];
    const float* w_out1 = (const float*)d_in[6];
    const float* w_out2 = (const float*)d_in[7];
    const int*   inputs = (const int*)d_in[8];
    float* probs = (float*)d_out;
    float* psi   = (float*)d_out + 2048;      // 32*64 probs, then 32*2^19 psi
    float* tab   = (float*)d_ws;              // 54 tables x 1 MiB float2 = 54 MiB
    unsigned* bar = (unsigned*)((char*)d_ws + (size_t)54 * 1024 * 1024);

    hipMemsetAsync(bar, 0, 2 * sizeof(unsigned), stream);
    mega_kernel<<<512, 256, 0, stream>>>(batch, w_in1, w_in2, w_u, w_k1, w_k2,
                                         w_out1, w_out2, inputs, tab, bar,
                                         psi, probs);
}

// Round 12
// 368.032 us; speedup vs baseline: 2.1357x; 2.1357x over previous
//
#include <hip/hip_runtime.h>
#include <math.h>

// RVQECell on MI355X.
// State: [B=32][2^19] fp32. Lane l <-> state bit (18-l). inout = bits 13..18,
// work = bits 1..12, ancilla = bit 0 (spectator).
//
// R17 (vs R16 fused @ 786 [707 kernel, spills]; R10 @ 328 = best):
//  R16 decomposition: harness-fixed overhead = 786-707 = 79 us -> R10's
//  split is 79 fixed + 154 main + ~95 (tables+out+gaps). Fusion upside was
//  ~20-40 us, not 110 -> abandoned. Spill cause: empirical allocator rule
//  cap = 256/launch_bounds_arg2 (R5-R8,R16: arg2=2 -> <=128, arg2=4 -> 64).
//  R17 = R10 3-kernel structure + two main_kernel changes:
//   (a) __launch_bounds__(256,1) -> VGPR cap 256. LDS (64 KiB) still binds
//       residency at 2 blocks/CU = 2 waves/EU, so occupancy unchanged.
//   (b) cross-barrier table PREFETCH: tload/compute split, A/B double-buffer
//       regs (12 float4 each); pass k+1's loads issue before pass k's
//       compute -> hides the per-pass global-load latency (the 43% idle).
//   (c) pass merge: U rotations commute -> reorder U layer to [U9,U6,Ulo]
//       and fuse U12 into N12's pass (uniform rots then table rots).
//       28 -> 25 passes (-3 LDS roundtrips, -3 barriers).
//  Guard: FETCH ~100/WRITE ~65 MB. If +100s MB -> spills -> revert (a,b).

#define BIAS_F 1.57079632679489662f

typedef float v4f __attribute__((ext_vector_type(4)));

__device__ __forceinline__ float4 ntload4(const float* p) {
    v4f v = __builtin_nontemporal_load((const v4f*)p);
    return make_float4(v.x, v.y, v.z, v.w);
}
__device__ __forceinline__ void ntstore4(float* p, float4 f) {
    v4f v = {f.x, f.y, f.z, f.w};
    __builtin_nontemporal_store(v, (v4f*)p);
}

// ---- LDS bank swizzle: fold bits 7..5 into 4..2 (keeps float4 contiguity) ----
__device__ __forceinline__ int SW(int i) { return i ^ ((i >> 3) & 0x1C); }
__device__ __forceinline__ float4 ldsld4(const float* st, int i) {
    return *(const float4*)&st[SW(i)];
}
__device__ __forceinline__ void ldsst4(float* st, int i, float4 v) {
    *(float4*)&st[SW(i)] = v;
}

#define LD2(p) (*(const float2*)(p))
#define LD4(p) (*(const float4*)(p))

// rotation on pairs (A.k, B.k); e = (c01,s01,c23,s23); .x/.y share angle (bit0)
__device__ __forceinline__ void rot4(float4& A, float4& B, float4 e) {
    float ax = A.x, ay = A.y, az = A.z, aw = A.w;
    A.x = e.x * ax - e.y * B.x;  B.x = e.y * ax + e.x * B.x;
    A.y = e.x * ay - e.y * B.y;  B.y = e.y * ay + e.x * B.y;
    A.z = e.z * az - e.w * B.z;  B.z = e.w * az + e.z * B.z;
    A.w = e.z * aw - e.w * B.w;  B.w = e.w * aw + e.z * B.w;
}
// rotation within a quad: pairs (x,z),(y,w)  (target = amp bit 1)
__device__ __forceinline__ void rotq(float4& P, float c, float s) {
    float px = P.x, py = P.y;
    P.x = c * px - s * P.z;  P.z = s * px + c * P.z;
    P.y = c * py - s * P.w;  P.w = s * py + c * P.w;
}

// Table layout: float2 tab2[n * 131072 + x] = {cos a, sin a}, n = 0..53.

// ============================ K1: tables ============================
__global__ __launch_bounds__(256) void tables_kernel(
    const float* __restrict__ w_in1, const float* __restrict__ w_in2,
    const float* __restrict__ w_k1,  const float* __restrict__ w_k2,
    const float* __restrict__ w_out1, const float* __restrict__ w_out2,
    float* __restrict__ tab)
{
    const int n = blockIdx.y;
    const int hi = blockIdx.x;       // x bits 16..8 (wave-uniform)
    const int tid = threadIdx.x;     // x bits 7..0
    const float* th1;
    const float* th2;
    if (n < 12)      { th1 = w_in1 + n * 17;         th2 = w_in2 + n * 289; }
    else if (n < 48) { th1 = w_k1 + (n - 12) * 17;   th2 = w_k2 + (n - 12) * 289; }
    else             { th1 = w_out1 + (n - 48) * 17; th2 = w_out2 + (n - 48) * 289; }

    // ---- wave-uniform hi part: phi_hi + cross coefficients C[a] ----
    float phi_hi = BIAS_F;
    float C[8];
#pragma unroll
    for (int a = 0; a < 8; ++a) C[a] = th1[9 + a];
#pragma unroll
    for (int i = 0; i < 9; ++i) {
        if ((hi >> (8 - i)) & 1) {
            float acc = th1[i];
#pragma unroll
            for (int j = i + 1; j < 9; ++j)
                if ((hi >> (8 - j)) & 1) acc += th2[i * 17 + j];
            phi_hi += acc;
#pragma unroll
            for (int a = 0; a < 8; ++a) C[a] += th2[i * 17 + 9 + a];
        }
    }

    // ---- per-thread lo part: 36 FMA ----
    float bt[8];
#pragma unroll
    for (int j = 0; j < 8; ++j) bt[j] = (float)((tid >> (7 - j)) & 1);
    float phi = phi_hi;
#pragma unroll
    for (int a = 0; a < 8; ++a) {
        float acc = C[a];
#pragma unroll
        for (int b2 = a + 1; b2 < 8; ++b2) acc += bt[b2] * th2[(9 + a) * 17 + 9 + b2];
        phi += bt[a] * acc;
    }

    float sp, cp;
    sincosf(phi, &sp, &cp);
    float c2 = cp * cp, s2 = sp * sp;
    float d = c2 * c2 + s2 * s2;           // >= 0.25 always
    float r = rsqrtf(d);
    r = r * (1.5f - 0.5f * d * r * r);     // one Newton step
    float2* dst = (float2*)tab + ((size_t)n * 131072 + (size_t)((hi << 8) | tid));
    *dst = make_float2(c2 * r, s2 * r);    // {cos a, sin a}
}

// ============================ K2: main fused ============================
struct TabRegs { float4 r[12]; };

// Load 12 table float4s for a hi pass (targets PA..PA-2). t* = float2 data,
// float-indexed (angle x at [2x]).
template <int PA>
__device__ __forceinline__ TabRegs tload_hi(const float* tA, const float* tB,
                                            const float* tC, int t8)
{
    const int lowb = PA - 4;
    const int low = t8 & ((1 << lowb) - 1);
    const int high = t8 >> lowb;
    const int x0 = (high << (PA - 1)) | (low << 1);
    const int dhi = (1 << PA) >> 2, dlo = (1 << PA) >> 3;
    TabRegs t;
    t.r[0]  = LD4(&tA[2 * x0]);            t.r[1]  = LD4(&tA[2 * (x0 + dlo)]);
    t.r[2]  = LD4(&tA[2 * (x0 + dhi)]);    t.r[3]  = LD4(&tA[2 * (x0 + dhi + dlo)]);
    t.r[4]  = LD4(&tB[2 * x0]);            t.r[5]  = LD4(&tB[2 * (x0 + dlo)]);
    t.r[6]  = LD4(&tB[2 * (x0 + dhi)]);    t.r[7]  = LD4(&tB[2 * (x0 + dhi + dlo)]);
    t.r[8]  = LD4(&tC[2 * x0]);            t.r[9]  = LD4(&tC[2 * (x0 + dlo)]);
    t.r[10] = LD4(&tC[2 * (x0 + dhi)]);    t.r[11] = LD4(&tC[2 * (x0 + dhi + dlo)]);
    return t;
}

// Load 12 table float4s for the lo pass (targets 3,2,1).
__device__ __forceinline__ TabRegs tload_lo(const float* tA, const float* tB,
                                            const float* tC, int t8)
{
    const int x0 = t8 << 3;
    TabRegs t;
    t.r[0]  = LD4(&tA[2 * x0]);      t.r[1]  = LD4(&tA[2 * x0 + 4]);
    t.r[2]  = LD4(&tA[2 * x0 + 8]);  t.r[3]  = LD4(&tA[2 * x0 + 12]);
    t.r[4]  = LD4(&tB[2 * x0]);      t.r[5]  = LD4(&tB[2 * x0 + 4]);
    t.r[6]  = LD4(&tB[2 * x0 + 8]);  t.r[7]  = LD4(&tB[2 * x0 + 12]);
    t.r[8]  = LD4(&tC[2 * x0]);      t.r[9]  = LD4(&tC[2 * x0 + 4]);
    t.r[10] = LD4(&tC[2 * x0 + 8]);  t.r[11] = LD4(&tC[2 * x0 + 12]);
    return t;
}

// Hi pass compute, targets {PA,PA-1,PA-2}. UNI: apply uniform rotations on
// the same targets FIRST (merged U+N pass); NEUR: then table rotations.
template <int PA, bool NEUR, bool UNI>
__device__ __forceinline__ void compute_hi(float* l0, float* l1, int t8,
    const TabRegs& tr,
    float cA, float sA, float cB, float sB, float cC, float sC)
{
    const int lowb = PA - 4;
    const int low = t8 & ((1 << lowb) - 1);
    const int high = t8 >> lowb;
    const int i0 = (high << (PA + 1)) | (low << 2);
    const int oa = 1 << PA, ob = oa >> 1, oc = oa >> 2;
#pragma unroll
    for (int s = 0; s < 2; ++s) {
        float* sl = (s == 0) ? l0 : l1;
        float4 Q000 = ldsld4(sl, i0),            Q001 = ldsld4(sl, i0 + oc);
        float4 Q010 = ldsld4(sl, i0 + ob),       Q011 = ldsld4(sl, i0 + ob + oc);
        float4 Q100 = ldsld4(sl, i0 + oa),       Q101 = ldsld4(sl, i0 + oa + oc);
        float4 Q110 = ldsld4(sl, i0 + oa + ob),  Q111 = ldsld4(sl, i0 + oa + ob + oc);
        if (UNI || !NEUR) {
            float4 eA = make_float4(cA, sA, cA, sA);
            rot4(Q000, Q100, eA); rot4(Q001, Q101, eA);
            rot4(Q010, Q110, eA); rot4(Q011, Q111, eA);
            float4 eB = make_float4(cB, sB, cB, sB);
            rot4(Q000, Q010, eB); rot4(Q001, Q011, eB);
            rot4(Q100, Q110, eB); rot4(Q101, Q111, eB);
            float4 eC = make_float4(cC, sC, cC, sC);
            rot4(Q000, Q001, eC); rot4(Q010, Q011, eC);
            rot4(Q100, Q101, eC); rot4(Q110, Q111, eC);
        }
        if (NEUR) {
            // target PA
            rot4(Q000, Q100, tr.r[0]); rot4(Q001, Q101, tr.r[1]);
            rot4(Q010, Q110, tr.r[2]); rot4(Q011, Q111, tr.r[3]);
            // target PA-1
            rot4(Q000, Q010, tr.r[4]); rot4(Q001, Q011, tr.r[5]);
            rot4(Q100, Q110, tr.r[6]); rot4(Q101, Q111, tr.r[7]);
            // target PA-2
            rot4(Q000, Q001, tr.r[8]);  rot4(Q010, Q011, tr.r[9]);
            rot4(Q100, Q101, tr.r[10]); rot4(Q110, Q111, tr.r[11]);
        }
        ldsst4(sl, i0, Q000);            ldsst4(sl, i0 + oc, Q001);
        ldsst4(sl, i0 + ob, Q010);       ldsst4(sl, i0 + ob + oc, Q011);
        ldsst4(sl, i0 + oa, Q100);       ldsst4(sl, i0 + oa + oc, Q101);
        ldsst4(sl, i0 + oa + ob, Q110);  ldsst4(sl, i0 + oa + ob + oc, Q111);
    }
}

// Lo pass compute, targets {3,2,1}.
template <bool NEUR>
__device__ __forceinline__ void compute_lo(float* l0, float* l1, int t8,
    const TabRegs& tr,
    float cA, float sA, float cB, float sB, float cC, float sC)
{
    const int i0 = t8 << 5;
#pragma unroll
    for (int s = 0; s < 2; ++s) {
        float* sl = (s == 0) ? l0 : l1;
        float4 Q0 = ldsld4(sl, i0),      Q1 = ldsld4(sl, i0 + 4);
        float4 Q2 = ldsld4(sl, i0 + 8),  Q3 = ldsld4(sl, i0 + 12);
        float4 Q4 = ldsld4(sl, i0 + 16), Q5 = ldsld4(sl, i0 + 20);
        float4 Q6 = ldsld4(sl, i0 + 24), Q7 = ldsld4(sl, i0 + 28);
        if (NEUR) {
            // target 3: pairs (k, k+2)
            rot4(Q0, Q2, tr.r[0]); rot4(Q1, Q3, tr.r[1]);
            rot4(Q4, Q6, tr.r[2]); rot4(Q5, Q7, tr.r[3]);
            // target 2: pairs (k, k+1)
            rot4(Q0, Q1, tr.r[4]); rot4(Q2, Q3, tr.r[5]);
            rot4(Q4, Q5, tr.r[6]); rot4(Q6, Q7, tr.r[7]);
            // target 1: in-quad
            rotq(Q0, tr.r[8].x,  tr.r[8].y);  rotq(Q1, tr.r[8].z,  tr.r[8].w);
            rotq(Q2, tr.r[9].x,  tr.r[9].y);  rotq(Q3, tr.r[9].z,  tr.r[9].w);
            rotq(Q4, tr.r[10].x, tr.r[10].y); rotq(Q5, tr.r[10].z, tr.r[10].w);
            rotq(Q6, tr.r[11].x, tr.r[11].y); rotq(Q7, tr.r[11].z, tr.r[11].w);
        } else {
            float4 eA = make_float4(cA, sA, cA, sA);
            rot4(Q0, Q2, eA); rot4(Q1, Q3, eA); rot4(Q4, Q6, eA); rot4(Q5, Q7, eA);
            float4 eB = make_float4(cB, sB, cB, sB);
            rot4(Q0, Q1, eB); rot4(Q2, Q3, eB); rot4(Q4, Q5, eB); rot4(Q6, Q7, eB);
            rotq(Q0, cC, sC); rotq(Q1, cC, sC); rotq(Q2, cC, sC); rotq(Q3, cC, sC);
            rotq(Q4, cC, sC); rotq(Q5, cC, sC); rotq(Q6, cC, sC); rotq(Q7, cC, sC);
        }
        ldsst4(sl, i0, Q0);      ldsst4(sl, i0 + 4, Q1);
        ldsst4(sl, i0 + 8, Q2);  ldsst4(sl, i0 + 12, Q3);
        ldsst4(sl, i0 + 16, Q4); ldsst4(sl, i0 + 20, Q5);
        ldsst4(sl, i0 + 24, Q6); ldsst4(sl, i0 + 28, Q7);
    }
}

// 1024 blocks x 256 threads, 2 batch slots (64 KiB LDS) per block.
// bounds (256,1): VGPR cap 256 (empirical rule 256/arg2). LDS binds
// residency at 2 blocks/CU = 2 waves/EU -> occupancy unchanged vs R10.
__global__ __launch_bounds__(256, 1) void main_kernel(
    const float* __restrict__ batch, const float* __restrict__ w_u,
    const int* __restrict__ inputs, const float* __restrict__ tab,
    float* __restrict__ psi, float* __restrict__ probs)
{
    __shared__ __align__(16) float lds[2][8192];   // 64 KiB: 2 batch slots
    const int t8 = threadIdx.x;
    const int blk = blockIdx.x;
    const int xcd = blk & 7;
    const int vt = (xcd << 3) | ((blk >> 3) & 7);   // table inout value
    const int pair = blk >> 6;                       // 0..15

    if (blk == 0) {   // zero probs for out_kernel atomics
        float4 z = make_float4(0.f, 0.f, 0.f, 0.f);
        *(float4*)&probs[t8 * 8] = z;
        *(float4*)&probs[t8 * 8 + 4] = z;
    }

    int bb[2], uu[2];
#pragma unroll
    for (int s = 0; s < 2; ++s) {
        int b = pair * 2 + s;
        int fb = 0;
#pragma unroll
        for (int i = 0; i < 6; ++i) fb |= (inputs[b * 6 + i] & 1) << (5 - i);
        bb[s] = b; uu[s] = vt ^ fb;
        const float* src = batch + ((size_t)b << 19) + ((size_t)uu[s] << 13);
#pragma unroll
        for (int k = 0; k < 8; ++k) {
            int i4 = (k * 256 + t8) * 4;
            float4 v = ntload4(&src[i4]);
            *(float4*)&lds[s][SW(i4)] = v;
        }
    }
    float* l0 = lds[0];
    float* l1 = lds[1];

    // float2 table base for this vt (float-indexed; angle x at [2x])
    const float* tb = tab + ((size_t)vt << 12);
#define TN(j) (tb + (size_t)(j) * 262144)
#define BAR __syncthreads()

    TabRegs A, B;
    A = tload_hi<12>(TN(0), TN(1), TN(2), t8);      // prefetch pass 0
    BAR;
    // ---- input layer (neurons 0..11), one-ahead prefetch ----
    B = tload_hi<9>(TN(3), TN(4), TN(5), t8);
    compute_hi<12, true, false>(l0, l1, t8, A, 0,0,0,0,0,0);  BAR;
    A = tload_hi<6>(TN(6), TN(7), TN(8), t8);
    compute_hi<9, true, false>(l0, l1, t8, B, 0,0,0,0,0,0);   BAR;
    B = tload_lo(TN(9), TN(10), TN(11), t8);
    compute_hi<6, true, false>(l0, l1, t8, A, 0,0,0,0,0,0);   BAR;
    A = tload_hi<12>(TN(12), TN(13), TN(14), t8);   // stage 0 merged-pass tables
    compute_lo<true>(l0, l1, t8, B, 0,0,0,0,0,0);             BAR;

#pragma unroll 1
    for (int st2 = 0; st2 < 3; ++st2) {
        const float* wu = w_u + st2 * 12;
        const int nb = 12 + st2 * 12;
        float c0, s0, c1, s1, c2, s2;
        // U layer reordered to [U9,U6,Ulo] then U12 merged into N12's pass
        // (single-qubit rotations on distinct targets commute).
        sincosf(wu[3], &s0, &c0); sincosf(wu[4], &s1, &c1); sincosf(wu[5], &s2, &c2);
        compute_hi<9, false, false>(l0, l1, t8, A, c0,s0, c1,s1, c2,s2);  BAR;
        sincosf(wu[6], &s0, &c0); sincosf(wu[7], &s1, &c1); sincosf(wu[8], &s2, &c2);
        compute_hi<6, false, false>(l0, l1, t8, A, c0,s0, c1,s1, c2,s2);  BAR;
        sincosf(wu[9], &s0, &c0); sincosf(wu[10], &s1, &c1); sincosf(wu[11], &s2, &c2);
        compute_lo<false>(l0, l1, t8, A, c0,s0, c1,s1, c2,s2);            BAR;

        // merged U12+N12 (A holds nb+0..2 tables, prefetched last iteration)
        sincosf(wu[0], &s0, &c0); sincosf(wu[1], &s1, &c1); sincosf(wu[2], &s2, &c2);
        B = tload_hi<9>(TN(nb+3), TN(nb+4), TN(nb+5), t8);
        compute_hi<12, true, true>(l0, l1, t8, A, c0,s0, c1,s1, c2,s2);   BAR;
        A = tload_hi<6>(TN(nb+6), TN(nb+7), TN(nb+8), t8);
        compute_hi<9, true, false>(l0, l1, t8, B, 0,0,0,0,0,0);           BAR;
        B = tload_lo(TN(nb+9), TN(nb+10), TN(nb+11), t8);
        compute_hi<6, true, false>(l0, l1, t8, A, 0,0,0,0,0,0);           BAR;
        if (st2 < 2)
            A = tload_hi<12>(TN(nb+12), TN(nb+13), TN(nb+14), t8);
        compute_lo<true>(l0, l1, t8, B, 0,0,0,0,0,0);                     BAR;
    }
#undef TN
#undef BAR

#pragma unroll
    for (int s = 0; s < 2; ++s) {
        float* dst = psi + ((size_t)bb[s] << 19) + ((size_t)uu[s] << 13);
#pragma unroll
        for (int k = 0; k < 8; ++k) {
            int i4 = (k * 256 + t8) * 4;
            float4 v = *(const float4*)&lds[s][SW(i4)];
            ntstore4(&dst[i4], v);
        }
    }
}

// ============================ K3: output layer + probs ============================
// Tile 64 k x 256 cols through LDS (XOR-swizzled, conflict-free). Tables are
// unpacked float2 -> no dec() in the butterfly chain. ev staged 16-at-a-time
// to bound load hoisting (a[64] + 32 ev regs ~ 110 < 128).
__global__ __launch_bounds__(256, 2) void out_kernel(
    const float* __restrict__ tab, float* __restrict__ psi,
    float* __restrict__ probs)
{
    __shared__ __align__(16) float ts[16384];   // 64 KiB tile
    const int tid = threadIdx.x;
    const int lane = tid & 63;
    const int wv = tid >> 6;
    const int b = blockIdx.x >> 5;
    const int c0 = (blockIdx.x & 31) << 8;
    float* gbase = psi + ((size_t)b << 19) + c0;

    // ---- load: wave wv loads rows wv*16..wv*16+15, lane l -> cols 4l..4l+3 ----
#pragma unroll
    for (int i = 0; i < 16; ++i) {
        int k = wv * 16 + i;
        float4 v = ntload4(&gbase[((size_t)k << 13) + lane * 4]);
        int f4 = lane ^ (k & 15);
        *(float4*)&ts[k * 256 + f4 * 4] = v;
    }
    __syncthreads();

    // ---- column phase: thread owns col c = tid ----
    float a[64];
#pragma unroll
    for (int k = 0; k < 64; ++k) a[k] = ts[k * 256 + (tid ^ ((k & 15) << 2))];
    const int w12 = (c0 | tid) >> 1;

#define OSTAGE(J) { \
    const float* tj = tab + 2u * ((size_t)(48 + (J)) * 131072 + (size_t)w12); \
    _Pragma("unroll") \
    for (int h = 0; h < 2; ++h) { \
        float2 ev[16]; \
        _Pragma("unroll") \
        for (int m = 0; m < 16; ++m) ev[m] = LD2(&tj[(size_t)(h * 16 + m) << 13]); \
        _Pragma("unroll") \
        for (int m = 0; m < 16; ++m) { \
            const int mm = h * 16 + m; \
            const int q = 5 - (J); \
            const int k0 = ((mm >> q) << (q + 1)) | (mm & ((1 << q) - 1)); \
            const int k1 = k0 | (1 << q); \
            float2 e = ev[m]; \
            float A0 = a[k0], A1 = a[k1]; \
            a[k0] = e.x * A0 - e.y * A1; \
            a[k1] = e.y * A0 + e.x * A1; } } }
    OSTAGE(0) OSTAGE(1) OSTAGE(2) OSTAGE(3) OSTAGE(4) OSTAGE(5)
#undef OSTAGE

#pragma unroll
    for (int k = 0; k < 64; ++k) ts[k * 256 + (tid ^ ((k & 15) << 2))] = a[k];
    __syncthreads();

    // ---- store rows back (float4) ----
#pragma unroll
    for (int i = 0; i < 16; ++i) {
        int k = wv * 16 + i;
        int f4 = lane ^ (k & 15);
        float4 v = *(const float4*)&ts[k * 256 + f4 * 4];
        ntstore4(&gbase[((size_t)k << 13) + lane * 4], v);
    }

    // ---- probs: thread (seg=tid>>6, k=tid&63) sums 64 cols, rotated start ----
    const int k6 = tid & 63, seg = tid >> 6;
    float p = 0.f;
#pragma unroll
    for (int j = 0; j < 64; ++j) {
        int c = seg * 64 + ((j + k6) & 63);
        float v = ts[k6 * 256 + (c ^ ((k6 & 15) << 2))];
        p += v * v;
    }
    atomicAdd(&probs[b * 64 + k6], p);
}

// ============================ launch ============================
extern "C" void kernel_launch(void* const* d_in, const int* in_sizes, int n_in,
                              void* d_out, int out_size, void* d_ws, size_t ws_size,
                              hipStream_t stream)
{
    const float* batch  = (const float*)d_in[0];
    const float* w_in1  = (const float*)d_in[1];
    const float* w_in2  = (const float*)d_in[2];
    const float* w_u    = (const float*)d_in[3];
    const float* w_k1   = (const float*)d_in[4];
    const float* w_k2   = (const float*)d_in[5];
    const float* w_out1 = (const float*)d_in[6];
    const float* w_out2 = (const float*)d_in[7];
    const int*   inputs = (const int*)d_in[8];
    float* probs = (float*)d_out;
    float* psi   = (float*)d_out + 2048;      // 32*64 probs, then 32*2^19 psi
    float* tab   = (float*)d_ws;              // 54 tables x 1 MiB float2 = 54 MiB

    tables_kernel<<<dim3(512, 54), 256, 0, stream>>>(w_in1, w_in2, w_k1, w_k2,
                                                     w_out1, w_out2, tab);
    main_kernel<<<1024, 256, 0, stream>>>(batch, w_u, inputs, tab, psi, probs);
    out_kernel<<<1024, 256, 0, stream>>>(tab, psi, probs);
}

// Round 13
// 322.318 us; speedup vs baseline: 2.4386x; 1.1418x over previous
//
#include <hip/hip_runtime.h>
#include <math.h>

// RVQECell on MI355X.
// State: [B=32][2^19] fp32. Lane l <-> state bit (18-l). inout = bits 13..18,
// work = bits 1..12, ancilla = bit 0 (spectator).
//
// R18 (vs R17 @ 368 [main 197]; R10 @ 328 = best [main 154]):
//  R17 post-mortem: launch_bounds arg2 is a HARD waves/EU residency setting
//  on this toolchain (6 data points: arg2=1->11.7%, 2->20-22%, 4->39-42%
//  occupancy, regardless of LDS/VGPR headroom). arg2=1 halved TLP -> 197 us
//  despite prefetch. Salvage from R17 (both correctness-proven):
//   (a) U12->N12 pass merge: 28 -> 25 passes (-3 LDS roundtrips/barriers);
//   (b) SINGLE-buffer prefetch: during the 3 uniform passes no table regs
//       are live -> load the merged pass's 12 float4s before U9, consume 4
//       barriers later. +48 VGPR only where pressure is low -> fits 128.
//  R18 = R10 structure + (a) + (b), launch_bounds(256,2) restored.
//  Guard: VGPR <= 128, WRITE ~65 MB (spill -> revert prefetch).

#define BIAS_F 1.57079632679489662f

typedef float v4f __attribute__((ext_vector_type(4)));

__device__ __forceinline__ float4 ntload4(const float* p) {
    v4f v = __builtin_nontemporal_load((const v4f*)p);
    return make_float4(v.x, v.y, v.z, v.w);
}
__device__ __forceinline__ void ntstore4(float* p, float4 f) {
    v4f v = {f.x, f.y, f.z, f.w};
    __builtin_nontemporal_store(v, (v4f*)p);
}

// ---- LDS bank swizzle: fold bits 7..5 into 4..2 (keeps float4 contiguity) ----
__device__ __forceinline__ int SW(int i) { return i ^ ((i >> 3) & 0x1C); }
__device__ __forceinline__ float4 ldsld4(const float* st, int i) {
    return *(const float4*)&st[SW(i)];
}
__device__ __forceinline__ void ldsst4(float* st, int i, float4 v) {
    *(float4*)&st[SW(i)] = v;
}

#define LD2(p) (*(const float2*)(p))
#define LD4(p) (*(const float4*)(p))

// rotation on pairs (A.k, B.k); e = (c01,s01,c23,s23); .x/.y share angle (bit0)
__device__ __forceinline__ void rot4(float4& A, float4& B, float4 e) {
    float ax = A.x, ay = A.y, az = A.z, aw = A.w;
    A.x = e.x * ax - e.y * B.x;  B.x = e.y * ax + e.x * B.x;
    A.y = e.x * ay - e.y * B.y;  B.y = e.y * ay + e.x * B.y;
    A.z = e.z * az - e.w * B.z;  B.z = e.w * az + e.z * B.z;
    A.w = e.z * aw - e.w * B.w;  B.w = e.w * aw + e.z * B.w;
}
// rotation within a quad: pairs (x,z),(y,w)  (target = amp bit 1)
__device__ __forceinline__ void rotq(float4& P, float c, float s) {
    float px = P.x, py = P.y;
    P.x = c * px - s * P.z;  P.z = s * px + c * P.z;
    P.y = c * py - s * P.w;  P.w = s * py + c * P.w;
}

// Table layout: float2 tab2[n * 131072 + x] = {cos a, sin a}, n = 0..53.

// ============================ K1: tables ============================
__global__ __launch_bounds__(256) void tables_kernel(
    const float* __restrict__ w_in1, const float* __restrict__ w_in2,
    const float* __restrict__ w_k1,  const float* __restrict__ w_k2,
    const float* __restrict__ w_out1, const float* __restrict__ w_out2,
    float* __restrict__ tab)
{
    const int n = blockIdx.y;
    const int hi = blockIdx.x;       // x bits 16..8 (wave-uniform)
    const int tid = threadIdx.x;     // x bits 7..0
    const float* th1;
    const float* th2;
    if (n < 12)      { th1 = w_in1 + n * 17;         th2 = w_in2 + n * 289; }
    else if (n < 48) { th1 = w_k1 + (n - 12) * 17;   th2 = w_k2 + (n - 12) * 289; }
    else             { th1 = w_out1 + (n - 48) * 17; th2 = w_out2 + (n - 48) * 289; }

    // ---- wave-uniform hi part: phi_hi + cross coefficients C[a] ----
    float phi_hi = BIAS_F;
    float C[8];
#pragma unroll
    for (int a = 0; a < 8; ++a) C[a] = th1[9 + a];
#pragma unroll
    for (int i = 0; i < 9; ++i) {
        if ((hi >> (8 - i)) & 1) {
            float acc = th1[i];
#pragma unroll
            for (int j = i + 1; j < 9; ++j)
                if ((hi >> (8 - j)) & 1) acc += th2[i * 17 + j];
            phi_hi += acc;
#pragma unroll
            for (int a = 0; a < 8; ++a) C[a] += th2[i * 17 + 9 + a];
        }
    }

    // ---- per-thread lo part: 36 FMA ----
    float bt[8];
#pragma unroll
    for (int j = 0; j < 8; ++j) bt[j] = (float)((tid >> (7 - j)) & 1);
    float phi = phi_hi;
#pragma unroll
    for (int a = 0; a < 8; ++a) {
        float acc = C[a];
#pragma unroll
        for (int b2 = a + 1; b2 < 8; ++b2) acc += bt[b2] * th2[(9 + a) * 17 + 9 + b2];
        phi += bt[a] * acc;
    }

    float sp, cp;
    sincosf(phi, &sp, &cp);
    float c2 = cp * cp, s2 = sp * sp;
    float d = c2 * c2 + s2 * s2;           // >= 0.25 always
    float r = rsqrtf(d);
    r = r * (1.5f - 0.5f * d * r * r);     // one Newton step
    float2* dst = (float2*)tab + ((size_t)n * 131072 + (size_t)((hi << 8) | tid));
    *dst = make_float2(c2 * r, s2 * r);    // {cos a, sin a}
}

// ============================ K2: main fused ============================
struct TabRegs { float4 r[12]; };

// Load 12 table float4s for a hi pass (targets PA..PA-2).
template <int PA>
__device__ __forceinline__ TabRegs tload_hi(const float* tA, const float* tB,
                                            const float* tC, int t8)
{
    const int lowb = PA - 4;
    const int low = t8 & ((1 << lowb) - 1);
    const int high = t8 >> lowb;
    const int x0 = (high << (PA - 1)) | (low << 1);
    const int dhi = (1 << PA) >> 2, dlo = (1 << PA) >> 3;
    TabRegs t;
    t.r[0]  = LD4(&tA[2 * x0]);            t.r[1]  = LD4(&tA[2 * (x0 + dlo)]);
    t.r[2]  = LD4(&tA[2 * (x0 + dhi)]);    t.r[3]  = LD4(&tA[2 * (x0 + dhi + dlo)]);
    t.r[4]  = LD4(&tB[2 * x0]);            t.r[5]  = LD4(&tB[2 * (x0 + dlo)]);
    t.r[6]  = LD4(&tB[2 * (x0 + dhi)]);    t.r[7]  = LD4(&tB[2 * (x0 + dhi + dlo)]);
    t.r[8]  = LD4(&tC[2 * x0]);            t.r[9]  = LD4(&tC[2 * (x0 + dlo)]);
    t.r[10] = LD4(&tC[2 * (x0 + dhi)]);    t.r[11] = LD4(&tC[2 * (x0 + dhi + dlo)]);
    return t;
}

// Load 12 table float4s for the lo pass (targets 3,2,1).
__device__ __forceinline__ TabRegs tload_lo(const float* tA, const float* tB,
                                            const float* tC, int t8)
{
    const int x0 = t8 << 3;
    TabRegs t;
    t.r[0]  = LD4(&tA[2 * x0]);      t.r[1]  = LD4(&tA[2 * x0 + 4]);
    t.r[2]  = LD4(&tA[2 * x0 + 8]);  t.r[3]  = LD4(&tA[2 * x0 + 12]);
    t.r[4]  = LD4(&tB[2 * x0]);      t.r[5]  = LD4(&tB[2 * x0 + 4]);
    t.r[6]  = LD4(&tB[2 * x0 + 8]);  t.r[7]  = LD4(&tB[2 * x0 + 12]);
    t.r[8]  = LD4(&tC[2 * x0]);      t.r[9]  = LD4(&tC[2 * x0 + 4]);
    t.r[10] = LD4(&tC[2 * x0 + 8]);  t.r[11] = LD4(&tC[2 * x0 + 12]);
    return t;
}

// Hi pass compute, targets {PA,PA-1,PA-2}. UNI: uniform rots first (merged
// U+N pass); NEUR: table rots.
template <int PA, bool NEUR, bool UNI>
__device__ __forceinline__ void compute_hi(float* l0, float* l1, int t8,
    const TabRegs& tr,
    float cA, float sA, float cB, float sB, float cC, float sC)
{
    const int lowb = PA - 4;
    const int low = t8 & ((1 << lowb) - 1);
    const int high = t8 >> lowb;
    const int i0 = (high << (PA + 1)) | (low << 2);
    const int oa = 1 << PA, ob = oa >> 1, oc = oa >> 2;
#pragma unroll
    for (int s = 0; s < 2; ++s) {
        float* sl = (s == 0) ? l0 : l1;
        float4 Q000 = ldsld4(sl, i0),            Q001 = ldsld4(sl, i0 + oc);
        float4 Q010 = ldsld4(sl, i0 + ob),       Q011 = ldsld4(sl, i0 + ob + oc);
        float4 Q100 = ldsld4(sl, i0 + oa),       Q101 = ldsld4(sl, i0 + oa + oc);
        float4 Q110 = ldsld4(sl, i0 + oa + ob),  Q111 = ldsld4(sl, i0 + oa + ob + oc);
        if (UNI || !NEUR) {
            float4 eA = make_float4(cA, sA, cA, sA);
            rot4(Q000, Q100, eA); rot4(Q001, Q101, eA);
            rot4(Q010, Q110, eA); rot4(Q011, Q111, eA);
            float4 eB = make_float4(cB, sB, cB, sB);
            rot4(Q000, Q010, eB); rot4(Q001, Q011, eB);
            rot4(Q100, Q110, eB); rot4(Q101, Q111, eB);
            float4 eC = make_float4(cC, sC, cC, sC);
            rot4(Q000, Q001, eC); rot4(Q010, Q011, eC);
            rot4(Q100, Q101, eC); rot4(Q110, Q111, eC);
        }
        if (NEUR) {
            // target PA
            rot4(Q000, Q100, tr.r[0]); rot4(Q001, Q101, tr.r[1]);
            rot4(Q010, Q110, tr.r[2]); rot4(Q011, Q111, tr.r[3]);
            // target PA-1
            rot4(Q000, Q010, tr.r[4]); rot4(Q001, Q011, tr.r[5]);
            rot4(Q100, Q110, tr.r[6]); rot4(Q101, Q111, tr.r[7]);
            // target PA-2
            rot4(Q000, Q001, tr.r[8]);  rot4(Q010, Q011, tr.r[9]);
            rot4(Q100, Q101, tr.r[10]); rot4(Q110, Q111, tr.r[11]);
        }
        ldsst4(sl, i0, Q000);            ldsst4(sl, i0 + oc, Q001);
        ldsst4(sl, i0 + ob, Q010);       ldsst4(sl, i0 + ob + oc, Q011);
        ldsst4(sl, i0 + oa, Q100);       ldsst4(sl, i0 + oa + oc, Q101);
        ldsst4(sl, i0 + oa + ob, Q110);  ldsst4(sl, i0 + oa + ob + oc, Q111);
    }
}

// Lo pass compute, targets {3,2,1}.
template <bool NEUR>
__device__ __forceinline__ void compute_lo(float* l0, float* l1, int t8,
    const TabRegs& tr,
    float cA, float sA, float cB, float sB, float cC, float sC)
{
    const int i0 = t8 << 5;
#pragma unroll
    for (int s = 0; s < 2; ++s) {
        float* sl = (s == 0) ? l0 : l1;
        float4 Q0 = ldsld4(sl, i0),      Q1 = ldsld4(sl, i0 + 4);
        float4 Q2 = ldsld4(sl, i0 + 8),  Q3 = ldsld4(sl, i0 + 12);
        float4 Q4 = ldsld4(sl, i0 + 16), Q5 = ldsld4(sl, i0 + 20);
        float4 Q6 = ldsld4(sl, i0 + 24), Q7 = ldsld4(sl, i0 + 28);
        if (NEUR) {
            // target 3: pairs (k, k+2)
            rot4(Q0, Q2, tr.r[0]); rot4(Q1, Q3, tr.r[1]);
            rot4(Q4, Q6, tr.r[2]); rot4(Q5, Q7, tr.r[3]);
            // target 2: pairs (k, k+1)
            rot4(Q0, Q1, tr.r[4]); rot4(Q2, Q3, tr.r[5]);
            rot4(Q4, Q5, tr.r[6]); rot4(Q6, Q7, tr.r[7]);
            // target 1: in-quad
            rotq(Q0, tr.r[8].x,  tr.r[8].y);  rotq(Q1, tr.r[8].z,  tr.r[8].w);
            rotq(Q2, tr.r[9].x,  tr.r[9].y);  rotq(Q3, tr.r[9].z,  tr.r[9].w);
            rotq(Q4, tr.r[10].x, tr.r[10].y); rotq(Q5, tr.r[10].z, tr.r[10].w);
            rotq(Q6, tr.r[11].x, tr.r[11].y); rotq(Q7, tr.r[11].z, tr.r[11].w);
        } else {
            float4 eA = make_float4(cA, sA, cA, sA);
            rot4(Q0, Q2, eA); rot4(Q1, Q3, eA); rot4(Q4, Q6, eA); rot4(Q5, Q7, eA);
            float4 eB = make_float4(cB, sB, cB, sB);
            rot4(Q0, Q1, eB); rot4(Q2, Q3, eB); rot4(Q4, Q5, eB); rot4(Q6, Q7, eB);
            rotq(Q0, cC, sC); rotq(Q1, cC, sC); rotq(Q2, cC, sC); rotq(Q3, cC, sC);
            rotq(Q4, cC, sC); rotq(Q5, cC, sC); rotq(Q6, cC, sC); rotq(Q7, cC, sC);
        }
        ldsst4(sl, i0, Q0);      ldsst4(sl, i0 + 4, Q1);
        ldsst4(sl, i0 + 8, Q2);  ldsst4(sl, i0 + 12, Q3);
        ldsst4(sl, i0 + 16, Q4); ldsst4(sl, i0 + 20, Q5);
        ldsst4(sl, i0 + 24, Q6); ldsst4(sl, i0 + 28, Q7);
    }
}

// 1024 blocks x 256 threads, 2 batch slots (64 KiB LDS) per block.
// bounds (256,2): proven sweet spot (VGPR cap 128, occupancy ~20%).
__global__ __launch_bounds__(256, 2) void main_kernel(
    const float* __restrict__ batch, const float* __restrict__ w_u,
    const int* __restrict__ inputs, const float* __restrict__ tab,
    float* __restrict__ psi, float* __restrict__ probs)
{
    __shared__ __align__(16) float lds[2][8192];   // 64 KiB: 2 batch slots
    const int t8 = threadIdx.x;
    const int blk = blockIdx.x;
    const int xcd = blk & 7;
    const int vt = (xcd << 3) | ((blk >> 3) & 7);   // table inout value
    const int pair = blk >> 6;                       // 0..15

    if (blk == 0) {   // zero probs for out_kernel atomics
        float4 z = make_float4(0.f, 0.f, 0.f, 0.f);
        *(float4*)&probs[t8 * 8] = z;
        *(float4*)&probs[t8 * 8 + 4] = z;
    }

    int bb[2], uu[2];
#pragma unroll
    for (int s = 0; s < 2; ++s) {
        int b = pair * 2 + s;
        int fb = 0;
#pragma unroll
        for (int i = 0; i < 6; ++i) fb |= (inputs[b * 6 + i] & 1) << (5 - i);
        bb[s] = b; uu[s] = vt ^ fb;
        const float* src = batch + ((size_t)b << 19) + ((size_t)uu[s] << 13);
#pragma unroll
        for (int k = 0; k < 8; ++k) {
            int i4 = (k * 256 + t8) * 4;
            float4 v = ntload4(&src[i4]);
            *(float4*)&lds[s][SW(i4)] = v;
        }
    }
    float* l0 = lds[0];
    float* l1 = lds[1];

    // float2 table base for this vt (float-indexed; angle x at [2x])
    const float* tb = tab + ((size_t)vt << 12);
#define TN(j) (tb + (size_t)(j) * 262144)
#define BAR __syncthreads()

    TabRegs T;
    T = tload_hi<12>(TN(0), TN(1), TN(2), t8);
    BAR;
    // ---- input layer (neurons 0..11) ----
    compute_hi<12, true, false>(l0, l1, t8, T, 0,0,0,0,0,0);  BAR;
    T = tload_hi<9>(TN(3), TN(4), TN(5), t8);
    compute_hi<9, true, false>(l0, l1, t8, T, 0,0,0,0,0,0);   BAR;
    T = tload_hi<6>(TN(6), TN(7), TN(8), t8);
    compute_hi<6, true, false>(l0, l1, t8, T, 0,0,0,0,0,0);   BAR;
    T = tload_lo(TN(9), TN(10), TN(11), t8);
    compute_lo<true>(l0, l1, t8, T, 0,0,0,0,0,0);             BAR;

#pragma unroll 1
    for (int st2 = 0; st2 < 3; ++st2) {
        const float* wu = w_u + st2 * 12;
        const int nb = 12 + st2 * 12;
        float c0, s0, c1, s1, c2, s2;

        // Single-buffer PREFETCH: merged-pass tables loaded now; the 3
        // uniform passes (no table regs live) hide the latency.
        T = tload_hi<12>(TN(nb+0), TN(nb+1), TN(nb+2), t8);

        // U layer reordered to [U9,U6,Ulo]; U12 merged into the N12 pass
        // (single-qubit rotations on distinct targets commute).
        sincosf(wu[3], &s0, &c0); sincosf(wu[4], &s1, &c1); sincosf(wu[5], &s2, &c2);
        compute_hi<9, false, false>(l0, l1, t8, T, c0,s0, c1,s1, c2,s2);  BAR;
        sincosf(wu[6], &s0, &c0); sincosf(wu[7], &s1, &c1); sincosf(wu[8], &s2, &c2);
        compute_hi<6, false, false>(l0, l1, t8, T, c0,s0, c1,s1, c2,s2);  BAR;
        sincosf(wu[9], &s0, &c0); sincosf(wu[10], &s1, &c1); sincosf(wu[11], &s2, &c2);
        compute_lo<false>(l0, l1, t8, T, c0,s0, c1,s1, c2,s2);            BAR;

        // merged U12+N12 (T holds nb+0..2 tables, prefetched above)
        sincosf(wu[0], &s0, &c0); sincosf(wu[1], &s1, &c1); sincosf(wu[2], &s2, &c2);
        compute_hi<12, true, true>(l0, l1, t8, T, c0,s0, c1,s1, c2,s2);   BAR;
        T = tload_hi<9>(TN(nb+3), TN(nb+4), TN(nb+5), t8);
        compute_hi<9, true, false>(l0, l1, t8, T, 0,0,0,0,0,0);           BAR;
        T = tload_hi<6>(TN(nb+6), TN(nb+7), TN(nb+8), t8);
        compute_hi<6, true, false>(l0, l1, t8, T, 0,0,0,0,0,0);           BAR;
        T = tload_lo(TN(nb+9), TN(nb+10), TN(nb+11), t8);
        compute_lo<true>(l0, l1, t8, T, 0,0,0,0,0,0);                     BAR;
    }
#undef TN
#undef BAR

#pragma unroll
    for (int s = 0; s < 2; ++s) {
        float* dst = psi + ((size_t)bb[s] << 19) + ((size_t)uu[s] << 13);
#pragma unroll
        for (int k = 0; k < 8; ++k) {
            int i4 = (k * 256 + t8) * 4;
            float4 v = *(const float4*)&lds[s][SW(i4)];
            ntstore4(&dst[i4], v);
        }
    }
}

// ============================ K3: output layer + probs ============================
// Tile 64 k x 256 cols through LDS (XOR-swizzled, conflict-free). Tables are
// unpacked float2 -> no dec() in the butterfly chain. ev staged 16-at-a-time
// to bound load hoisting (a[64] + 32 ev regs ~ 110 < 128).
__global__ __launch_bounds__(256, 2) void out_kernel(
    const float* __restrict__ tab, float* __restrict__ psi,
    float* __restrict__ probs)
{
    __shared__ __align__(16) float ts[16384];   // 64 KiB tile
    const int tid = threadIdx.x;
    const int lane = tid & 63;
    const int wv = tid >> 6;
    const int b = blockIdx.x >> 5;
    const int c0 = (blockIdx.x & 31) << 8;
    float* gbase = psi + ((size_t)b << 19) + c0;

    // ---- load: wave wv loads rows wv*16..wv*16+15, lane l -> cols 4l..4l+3 ----
#pragma unroll
    for (int i = 0; i < 16; ++i) {
        int k = wv * 16 + i;
        float4 v = ntload4(&gbase[((size_t)k << 13) + lane * 4]);
        int f4 = lane ^ (k & 15);
        *(float4*)&ts[k * 256 + f4 * 4] = v;
    }
    __syncthreads();

    // ---- column phase: thread owns col c = tid ----
    float a[64];
#pragma unroll
    for (int k = 0; k < 64; ++k) a[k] = ts[k * 256 + (tid ^ ((k & 15) << 2))];
    const int w12 = (c0 | tid) >> 1;

#define OSTAGE(J) { \
    const float* tj = tab + 2u * ((size_t)(48 + (J)) * 131072 + (size_t)w12); \
    _Pragma("unroll") \
    for (int h = 0; h < 2; ++h) { \
        float2 ev[16]; \
        _Pragma("unroll") \
        for (int m = 0; m < 16; ++m) ev[m] = LD2(&tj[(size_t)(h * 16 + m) << 13]); \
        _Pragma("unroll") \
        for (int m = 0; m < 16; ++m) { \
            const int mm = h * 16 + m; \
            const int q = 5 - (J); \
            const int k0 = ((mm >> q) << (q + 1)) | (mm & ((1 << q) - 1)); \
            const int k1 = k0 | (1 << q); \
            float2 e = ev[m]; \
            float A0 = a[k0], A1 = a[k1]; \
            a[k0] = e.x * A0 - e.y * A1; \
            a[k1] = e.y * A0 + e.x * A1; } } }
    OSTAGE(0) OSTAGE(1) OSTAGE(2) OSTAGE(3) OSTAGE(4) OSTAGE(5)
#undef OSTAGE

#pragma unroll
    for (int k = 0; k < 64; ++k) ts[k * 256 + (tid ^ ((k & 15) << 2))] = a[k];
    __syncthreads();

    // ---- store rows back (float4) ----
#pragma unroll
    for (int i = 0; i < 16; ++i) {
        int k = wv * 16 + i;
        int f4 = lane ^ (k & 15);
        float4 v = *(const float4*)&ts[k * 256 + f4 * 4];
        ntstore4(&gbase[((size_t)k << 13) + lane * 4], v);
    }

    // ---- probs: thread (seg=tid>>6, k=tid&63) sums 64 cols, rotated start ----
    const int k6 = tid & 63, seg = tid >> 6;
    float p = 0.f;
#pragma unroll
    for (int j = 0; j < 64; ++j) {
        int c = seg * 64 + ((j + k6) & 63);
        float v = ts[k6 * 256 + (c ^ ((k6 & 15) << 2))];
        p += v * v;
    }
    atomicAdd(&probs[b * 64 + k6], p);
}

// ============================ launch ============================
extern "C" void kernel_launch(void* const* d_in, const int* in_sizes, int n_in,
                              void* d_out, int out_size, void* d_ws, size_t ws_size,
                              hipStream_t stream)
{
    const float* batch  = (const float*)d_in[0];
    const float* w_in1  = (const float*)d_in[1];
    const float* w_in2  = (const float*)d_in[2];
    const float* w_u    = (const float*)d_in[3];
    const float* w_k1   = (const float*)d_in[4];
    const float* w_k2   = (const float*)d_in[5];
    const float* w_out1 = (const float*)d_in[6];
    const float* w_out2 = (const float*)d_in[7];
    const int*   inputs = (const int*)d_in[8];
    float* probs = (float*)d_out;
    float* psi   = (float*)d_out + 2048;      // 32*64 probs, then 32*2^19 psi
    float* tab   = (float*)d_ws;              // 54 tables x 1 MiB float2 = 54 MiB

    tables_kernel<<<dim3(512, 54), 256, 0, stream>>>(w_in1, w_in2, w_k1, w_k2,
                                                     w_out1, w_out2, tab);
    main_kernel<<<1024, 256, 0, stream>>>(batch, w_u, inputs, tab, psi, probs);
    out_kernel<<<1024, 256, 0, stream>>>(tab, psi, probs);
}